// Round 6
// baseline (1103.815 us; speedup 1.0000x reference)
//
#include <hip/hip_runtime.h>
#include <math.h>

using f4 = __attribute__((ext_vector_type(4))) float;

// ws layout (floats)
#define OFF_D   0                    // 16*64 (unpadded)
#define OFF_WT  1024                 // 3 * 16384, rotated: [k][i][(o4+k)&7][ol]
#define WS_FLOATS (1024 + 3*16384)   // 50176

__global__ __launch_bounds__(256) void init_kernel(
    const float* __restrict__ fw_x, const float* __restrict__ fw_y,
    const float* __restrict__ fw_z, float* __restrict__ ws)
{
    int gid = blockIdx.x * 256 + threadIdx.x;
    if (gid < 1024) {
        // D[k][n] = s_k * cos(pi * k * (2n+1) / 128), orthonormal DCT-II
        int k = gid >> 6, n = gid & 63;
        float s = (k == 0) ? 0.125f : sqrtf(2.0f / 64.0f);
        ws[OFF_D + gid] = s * cospif((float)((2 * n + 1) * k) / 128.0f);
    } else if (gid < WS_FLOATS) {
        int r = gid - 1024;
        int a = r / 16384;           // 0:z 1:y 2:x
        int q = r % 16384;
        int k = q >> 10, i = (q >> 5) & 31, o = q & 31;
        int o4 = o >> 2, ol = o & 3;
        int o4r = (o4 + k) & 7;      // rotate f4-slot by k: spreads phase-2 banks
        const float* fw = (a == 0) ? fw_z : (a == 1) ? fw_y : fw_x;  // fw[(i*32+o)*16+k]
        ws[OFF_WT + a * 16384 + k * 1024 + i * 32 + o4r * 4 + ol] = fw[(i * 32 + o) * 16 + k];
    }
}

// Union: Ul/Vl live during phases 1-3; FF weights overlay them afterwards (MODE==2).
union PhaseU {
    struct { f4 Ul[512]; f4 Vl[512]; } p;     // 16 KB
    struct { f4 w0s[512]; f4 w1s[512]; } ff;  // 16 KB  (w0 natural [i][j], w1 natural [j][o])
};

// One block = 4 slabs (64 positions x 32 channels) along AXIS.
// h_slab = D^T @ mix_k( D_trunc @ X_slab ).
// MODE: 0 = write h, 1 = accumulate into h, 2 = accumulate + fused FF + final write.
template<int AXIS, int MODE>
__global__ __launch_bounds__(256, 3) void axis_kernel(
    const float* __restrict__ x, float* __restrict__ h,
    const float* __restrict__ ws,
    const float* __restrict__ w0g, const float* __restrict__ w1g,
    const float* __restrict__ b0g, const float* __restrict__ b1g)
{
    __shared__ f4 Xl[2048];      // 32 KB: AXIS2: [s][m][i4]; else [m][s][i4]; reused as h-tile
    __shared__ PhaseU su;        // 16 KB
    __shared__ f4 Dl4[272];      // 4.25 KB: D padded, row stride 68 floats (17 f4)
    __shared__ f4 b0sh[16];
    __shared__ f4 b1sh[8];
    float* Dl = reinterpret_cast<float*>(Dl4);

    const int t = threadIdx.x;
    const int bid = blockIdx.x;            // 4096 = 4 * 64 * 16
    const int b  = bid >> 10;
    const int c1 = (bid >> 4) & 63;
    const int c2 = bid & 15;

    const float* Dg = ws + OFF_D;
    const float* Wt = ws + OFF_WT + (AXIS == 2 ? 0 : AXIS == 1 ? 16384 : 2 * 16384);

    int base, strideM, strideS;
    if (AXIS == 2) { base = ((b * 64 + c1) * 64 + c2 * 4) * 2048; strideM = 32;     strideS = 2048; }
    if (AXIS == 1) { base = (b * 64 + c1) * 131072 + c2 * 128;    strideM = 2048;   strideS = 32; }
    if (AXIS == 0) { base = b * 8388608 + c1 * 2048 + c2 * 128;   strideM = 131072; strideS = 32; }

    // stage D with padded row stride (bank-spread for b32/b128 reads)
    #pragma unroll
    for (int q = 0; q < 4; ++q) {
        int idx = t + 256 * q;             // 0..1023
        int k = idx >> 6, n = idx & 63;
        Dl[k * 68 + n] = Dg[idx];
    }
    if constexpr (MODE == 2) {
        if (t < 16) b0sh[t] = reinterpret_cast<const f4*>(b0g)[t];
        else if (t < 24) b1sh[t - 16] = reinterpret_cast<const f4*>(b1g)[t - 16];
    }

    // stage X tile
    const f4* xg = reinterpret_cast<const f4*>(x);
    if (AXIS == 2) {
        int b4 = base >> 2;                // fully contiguous tile
        #pragma unroll
        for (int q = 0; q < 8; ++q) Xl[t + 256 * q] = xg[b4 + t + 256 * q];
    } else {
        #pragma unroll
        for (int q = 0; q < 8; ++q) {
            int j = t + 256 * q;
            int m = j >> 5, c = j & 31;    // per-m chunk: 128 contiguous floats [s][i]
            Xl[j] = xg[((base + m * strideM) >> 2) + c];
        }
    }
    __syncthreads();

    // Phase 1: U[s][k][i4] = sum_m D[k][m] * X[s][m][i4]; thread = (s,kp,i4), k = 2kp,2kp+1
    {
        const int i4 = t & 7, kp = (t >> 3) & 7, s = t >> 6;
        const int k0 = kp * 2;
        f4 a0 = {0.f, 0.f, 0.f, 0.f}, a1 = a0;
        #pragma unroll
        for (int mq = 0; mq < 16; ++mq) {
            f4 d0 = Dl4[k0 * 17 + mq];
            f4 d1 = Dl4[(k0 + 1) * 17 + mq];
            #pragma unroll
            for (int e = 0; e < 4; ++e) {
                int m = mq * 4 + e;
                f4 xv = Xl[AXIS == 2 ? (s * 512 + m * 8 + i4) : (m * 32 + s * 8 + i4)];
                a0 += xv * d0[e];
                a1 += xv * d1[e];
            }
        }
        su.p.Ul[s * 128 + k0 * 8 + i4] = a0;
        su.p.Ul[s * 128 + (k0 + 1) * 8 + i4] = a1;
    }
    __syncthreads();

    // Phase 2: V[s][k][o4] = sum_i U[s][k][i] * W[k][i][o4]; thread = (k,o4,sh), s = 2sh,2sh+1
    {
        const int k = t >> 4, o4 = (t >> 1) & 7, sh = t & 1;
        const int o4r = (o4 + k) & 7;      // matches init rotation
        const f4* Wt4 = reinterpret_cast<const f4*>(Wt);
        const float* Us = reinterpret_cast<const float*>(su.p.Ul);
        f4 v0 = {0.f, 0.f, 0.f, 0.f}, v1 = v0;
        #pragma unroll
        for (int ii = 0; ii < 32; ++ii) {
            int i = (ii + 4 * k) & 31;     // rotate loop start: spreads Us banks per k
            f4 w = Wt4[k * 256 + i * 8 + o4r];
            v0 += w * Us[(sh * 2) * 512 + k * 32 + i];
            v1 += w * Us[(sh * 2 + 1) * 512 + k * 32 + i];
        }
        su.p.Vl[(sh * 2) * 128 + k * 8 + o4] = v0;
        su.p.Vl[(sh * 2 + 1) * 128 + k * 8 + o4] = v1;
    }
    __syncthreads();

    // Phase 3: acc[n] = sum_k D[k][n] * V[s][k][o4]; thread = (o4,nc,s) owns 8 n's
    f4* hg = reinterpret_cast<f4*>(h);
    const int o4 = t & 7, nc = (t >> 3) & 7, s = t >> 6;
    {
        const int n0 = nc * 8;
        f4 acc[8];
        #pragma unroll
        for (int j = 0; j < 8; ++j) acc[j] = f4{0.f, 0.f, 0.f, 0.f};
        #pragma unroll
        for (int k = 0; k < 16; ++k) {
            f4 v  = su.p.Vl[s * 128 + k * 8 + o4];
            f4 d0 = Dl4[k * 17 + nc * 2];
            f4 d1 = Dl4[k * 17 + nc * 2 + 1];
            acc[0] += v * d0[0]; acc[1] += v * d0[1];
            acc[2] += v * d0[2]; acc[3] += v * d0[3];
            acc[4] += v * d1[0]; acc[5] += v * d1[1];
            acc[6] += v * d1[2]; acc[7] += v * d1[3];
        }
        #pragma unroll
        for (int j = 0; j < 8; ++j) {
            int n = n0 + j;
            int hi4 = ((base + n * strideM + s * strideS) >> 2) + o4;
            if constexpr (MODE == 0) {
                hg[hi4] = acc[j];
            } else if constexpr (MODE == 1) {
                hg[hi4] = acc[j] + hg[hi4];
            } else {
                // stage swizzled h-tile into Xl for the fused FF
                Xl[(s * 64 + n) * 8 + (o4 ^ (n & 7))] = acc[j] + hg[hi4];
            }
        }
    }

    if constexpr (MODE == 2) {
        __syncthreads();   // Vl reads done; h-tile visible
        // FF weights overlay Ul/Vl (natural layouts, no transpose)
        const f4* w0g4 = reinterpret_cast<const f4*>(w0g);
        const f4* w1g4 = reinterpret_cast<const f4*>(w1g);
        su.ff.w0s[t] = w0g4[t];  su.ff.w0s[t + 256] = w0g4[t + 256];
        su.ff.w1s[t] = w1g4[t];  su.ff.w1s[t + 256] = w1g4[t + 256];
        __syncthreads();

        // FF: out = relu(h@w0+b0)@w1 + b1, one position per thread, pure-FMA z-chunk form
        const int sw = t & 7;
        f4 h0[8], out[8];
        #pragma unroll
        for (int q = 0; q < 8; ++q) {
            h0[q]  = Xl[t * 8 + (q ^ sw)];
            out[q] = b1sh[q];
        }
        #pragma unroll 1
        for (int jc = 0; jc < 4; ++jc) {   // hidden chunk of 16 (4 f4)
            f4 z0 = b0sh[jc * 4 + 0], z1 = b0sh[jc * 4 + 1];
            f4 z2 = b0sh[jc * 4 + 2], z3 = b0sh[jc * 4 + 3];
            #pragma unroll
            for (int i = 0; i < 32; ++i) {
                float hi = h0[i >> 2][i & 3];
                z0 += su.ff.w0s[i * 16 + jc * 4 + 0] * hi;
                z1 += su.ff.w0s[i * 16 + jc * 4 + 1] * hi;
                z2 += su.ff.w0s[i * 16 + jc * 4 + 2] * hi;
                z3 += su.ff.w0s[i * 16 + jc * 4 + 3] * hi;
            }
            #pragma unroll
            for (int u = 0; u < 4; ++u) {
                f4 zu = (u == 0) ? z0 : (u == 1) ? z1 : (u == 2) ? z2 : z3;
                #pragma unroll
                for (int e = 0; e < 4; ++e) {
                    float zz = fmaxf(zu[e], 0.f);
                    int j = jc * 16 + u * 4 + e;
                    #pragma unroll
                    for (int q = 0; q < 8; ++q)
                        out[q] += su.ff.w1s[j * 8 + q] * zz;
                }
            }
        }
        #pragma unroll
        for (int q = 0; q < 8; ++q) Xl[t * 8 + (q ^ sw)] = out[q];   // exclusive slots
        __syncthreads();

        // cooperative final store (same mapping as phase 3)
        #pragma unroll
        for (int j = 0; j < 8; ++j) {
            int n = nc * 8 + j;
            f4 v = Xl[(s * 64 + n) * 8 + (o4 ^ (n & 7))];
            hg[((base + n * strideM + s * strideS) >> 2) + o4] = v;
        }
    }
}

extern "C" void kernel_launch(void* const* d_in, const int* in_sizes, int n_in,
                              void* d_out, int out_size, void* d_ws, size_t ws_size,
                              hipStream_t stream)
{
    const float* x   = (const float*)d_in[0];
    const float* fwx = (const float*)d_in[1];
    const float* fwy = (const float*)d_in[2];
    const float* fwz = (const float*)d_in[3];
    const float* w0  = (const float*)d_in[4];
    const float* b0  = (const float*)d_in[5];
    const float* w1  = (const float*)d_in[6];
    const float* b1  = (const float*)d_in[7];
    float* out = (float*)d_out;
    float* ws  = (float*)d_ws;

    if (ws_size < WS_FLOATS * sizeof(float)) return;

    init_kernel<<<(WS_FLOATS + 255) / 256, 256, 0, stream>>>(fwx, fwy, fwz, ws);
    // h accumulates in d_out (same shape/layout as output)
    axis_kernel<2, 0><<<4096, 256, 0, stream>>>(x, out, ws, w0, w1, b0, b1);
    axis_kernel<1, 1><<<4096, 256, 0, stream>>>(x, out, ws, w0, w1, b0, b1);
    axis_kernel<0, 2><<<4096, 256, 0, stream>>>(x, out, ws, w0, w1, b0, b1);  // + fused FF
}

// Round 8
// 1083.793 us; speedup vs baseline: 1.0185x; 1.0185x over previous
//
#include <hip/hip_runtime.h>
#include <math.h>

using f4 = __attribute__((ext_vector_type(4))) float;

// ws layout (floats)
#define OFF_D   0                    // 16*64 (unpadded)
#define OFF_WT  1024                 // 3 * 16384, rotated: [k][i][(o4+k)&7][ol]
#define WS_FLOATS (1024 + 3*16384)   // 50176
#define GRID 4096

__global__ __launch_bounds__(256) void init_kernel(
    const float* __restrict__ fw_x, const float* __restrict__ fw_y,
    const float* __restrict__ fw_z, float* __restrict__ ws)
{
    int gid = blockIdx.x * 256 + threadIdx.x;
    if (gid < 1024) {
        // D[k][n] = s_k * cos(pi * k * (2n+1) / 128), orthonormal DCT-II
        int k = gid >> 6, n = gid & 63;
        float s = (k == 0) ? 0.125f : sqrtf(2.0f / 64.0f);
        ws[OFF_D + gid] = s * cospif((float)((2 * n + 1) * k) / 128.0f);
    } else if (gid < WS_FLOATS) {
        int r = gid - 1024;
        int a = r / 16384;           // 0:z 1:y 2:x
        int q = r % 16384;
        int k = q >> 10, i = (q >> 5) & 31, o = q & 31;
        int o4 = o >> 2, ol = o & 3;
        int o4r = (o4 + k) & 7;      // rotate f4-slot by k: spreads phase-2 banks
        const float* fw = (a == 0) ? fw_z : (a == 1) ? fw_y : fw_x;  // fw[(i*32+o)*16+k]
        ws[OFF_WT + a * 16384 + k * 1024 + i * 32 + o4r * 4 + ol] = fw[(i * 32 + o) * 16 + k];
    }
}

// Union: Ul/Vl live during phases 1-3; FF weights overlay them afterwards (MODE==2).
union PhaseU {
    struct { f4 Ul[512]; f4 Vl[512]; } p;     // 16 KB
    struct { f4 w0s[512]; f4 w1s[512]; } ff;  // 16 KB  (w0 natural [i][j], w1 natural [j][o])
};

// One block = 4 slabs (64 positions x 32 channels) along AXIS.
// h_slab = D^T @ mix_k( D_trunc @ X_slab ).
// MODE: 0 = write h, 1 = accumulate into h, 2 = accumulate + fused FF + final write.
// ALL global h traffic uses the R3-validated it-sweep order (s-coherent in time);
// per-thread j-blocked MAC results bounce through swizzled LDS.
template<int AXIS, int MODE>
__global__ __launch_bounds__(256, 3) void axis_kernel(
    const float* __restrict__ x, float* __restrict__ h,
    const float* __restrict__ ws,
    const float* __restrict__ w0g, const float* __restrict__ w1g,
    const float* __restrict__ b0g, const float* __restrict__ b1g)
{
    __shared__ f4 Xl[2048];      // 32 KB: X tile during phases 1-2; h-tile afterwards
    __shared__ PhaseU su;        // 16 KB
    __shared__ f4 Dl4[272];      // 4.25 KB: D padded, row stride 68 floats (17 f4)
    __shared__ f4 b0sh[16];
    __shared__ f4 b1sh[8];
    float* Dl = reinterpret_cast<float*>(Dl4);

    const int t = threadIdx.x;
    // XCD-aware bijective swizzle (GRID % 8 == 0): each XCD gets a contiguous
    // logical chunk -> c2-groups sharing 8KB rows + the 64KB Wt table co-locate.
    const int bid = (blockIdx.x & 7) * (GRID >> 3) + (blockIdx.x >> 3);
    const int b  = bid >> 10;
    const int c1 = (bid >> 4) & 63;
    const int c2 = bid & 15;

    const float* Dg = ws + OFF_D;
    const float* Wt = ws + OFF_WT + (AXIS == 2 ? 0 : AXIS == 1 ? 16384 : 2 * 16384);

    int base, strideM, strideS;
    if (AXIS == 2) { base = ((b * 64 + c1) * 64 + c2 * 4) * 2048; strideM = 32;     strideS = 2048; }
    if (AXIS == 1) { base = (b * 64 + c1) * 131072 + c2 * 128;    strideM = 2048;   strideS = 32; }
    if (AXIS == 0) { base = b * 8388608 + c1 * 2048 + c2 * 128;   strideM = 131072; strideS = 32; }

    // stage D with padded row stride (bank-spread for b32/b128 reads)
    #pragma unroll
    for (int q = 0; q < 4; ++q) {
        int idx = t + 256 * q;             // 0..1023
        int k = idx >> 6, n = idx & 63;
        Dl[k * 68 + n] = Dg[idx];
    }
    if constexpr (MODE == 2) {
        if (t < 16) b0sh[t] = reinterpret_cast<const f4*>(b0g)[t];
        else if (t < 24) b1sh[t - 16] = reinterpret_cast<const f4*>(b1g)[t - 16];
    }

    // stage X tile
    const f4* xg = reinterpret_cast<const f4*>(x);
    if (AXIS == 2) {
        int b4 = base >> 2;                // fully contiguous tile
        #pragma unroll
        for (int q = 0; q < 8; ++q) Xl[t + 256 * q] = xg[b4 + t + 256 * q];
    } else {
        #pragma unroll
        for (int q = 0; q < 8; ++q) {
            int j = t + 256 * q;
            int m = j >> 5, c = j & 31;    // per-m chunk: 128 contiguous floats [s][i]
            Xl[j] = xg[((base + m * strideM) >> 2) + c];
        }
    }
    __syncthreads();

    // Phase 1: U[s][k][i4] = sum_m D[k][m] * X[s][m][i4]; thread = (s,kp,i4), k = 2kp,2kp+1
    {
        const int i4 = t & 7, kp = (t >> 3) & 7, s = t >> 6;
        const int k0 = kp * 2;
        f4 a0 = {0.f, 0.f, 0.f, 0.f}, a1 = a0;
        #pragma unroll
        for (int mq = 0; mq < 16; ++mq) {
            f4 d0 = Dl4[k0 * 17 + mq];
            f4 d1 = Dl4[(k0 + 1) * 17 + mq];
            #pragma unroll
            for (int e = 0; e < 4; ++e) {
                int m = mq * 4 + e;
                f4 xv = Xl[AXIS == 2 ? (s * 512 + m * 8 + i4) : (m * 32 + s * 8 + i4)];
                a0 += xv * d0[e];
                a1 += xv * d1[e];
            }
        }
        su.p.Ul[s * 128 + k0 * 8 + i4] = a0;
        su.p.Ul[s * 128 + (k0 + 1) * 8 + i4] = a1;
    }
    __syncthreads();

    // Phase 2: V[s][k][o4] = sum_i U[s][k][i] * W[k][i][o4]; thread = (k,o4,sh), s = 2sh,2sh+1
    {
        const int k = t >> 4, o4 = (t >> 1) & 7, sh = t & 1;
        const int o4r = (o4 + k) & 7;      // matches init rotation
        const f4* Wt4 = reinterpret_cast<const f4*>(Wt);
        const float* Us = reinterpret_cast<const float*>(su.p.Ul);
        f4 v0 = {0.f, 0.f, 0.f, 0.f}, v1 = v0;
        #pragma unroll
        for (int ii = 0; ii < 32; ++ii) {
            int i = (ii + 4 * k) & 31;     // rotate loop start: spreads Us banks per k
            f4 w = Wt4[k * 256 + i * 8 + o4r];
            v0 += w * Us[(sh * 2) * 512 + k * 32 + i];
            v1 += w * Us[(sh * 2 + 1) * 512 + k * 32 + i];
        }
        su.p.Vl[(sh * 2) * 128 + k * 8 + o4] = v0;
        su.p.Vl[(sh * 2 + 1) * 128 + k * 8 + o4] = v1;
    }
    __syncthreads();

    // Phase 3 MAC (j-blocked, LDS-only output): acc[n] = sum_k D[k][n] * V[s][k][o4]
    // thread (o4,nc,s) owns n = nc*8 + j; stage to Xl with XOR swizzle.
    {
        const int o4 = t & 7, nc = (t >> 3) & 7, s = t >> 6;
        f4 acc[8];
        #pragma unroll
        for (int j = 0; j < 8; ++j) acc[j] = f4{0.f, 0.f, 0.f, 0.f};
        #pragma unroll
        for (int k = 0; k < 16; ++k) {
            f4 v  = su.p.Vl[s * 128 + k * 8 + o4];
            f4 d0 = Dl4[k * 17 + nc * 2];
            f4 d1 = Dl4[k * 17 + nc * 2 + 1];
            acc[0] += v * d0[0]; acc[1] += v * d0[1];
            acc[2] += v * d0[2]; acc[3] += v * d0[3];
            acc[4] += v * d1[0]; acc[5] += v * d1[1];
            acc[6] += v * d1[2]; acc[7] += v * d1[3];
        }
        #pragma unroll
        for (int j = 0; j < 8; ++j) {
            int n = nc * 8 + j;
            Xl[(s * 64 + n) * 8 + (o4 ^ (n & 7))] = acc[j];
        }
    }
    __syncthreads();   // MAC done (Vl free), h-tile staged in Xl

    if constexpr (MODE == 2) {
        // FF weights overlay Ul/Vl; issue loads before the combine loop to overlap
        const f4* w0g4 = reinterpret_cast<const f4*>(w0g);
        const f4* w1g4 = reinterpret_cast<const f4*>(w1g);
        su.ff.w0s[t] = w0g4[t];  su.ff.w0s[t + 256] = w0g4[t + 256];
        su.ff.w1s[t] = w1g4[t];  su.ff.w1s[t + 256] = w1g4[t + 256];
    }

    // Global combine/store in the R3-validated it-sweep order:
    // per it: s = it>>1, n = (t>>3) + 32*(it&1), o4 = t&7  (s-coherent in time)
    f4* hg = reinterpret_cast<f4*>(h);
    #pragma unroll
    for (int it = 0; it < 8; ++it) {
        int n  = (t >> 3) + 32 * (it & 1);
        int s2 = it >> 1;
        int o4 = t & 7;
        int lds = (s2 * 64 + n) * 8 + (o4 ^ (n & 7));
        int hi4 = ((base + n * strideM + s2 * strideS) >> 2) + o4;
        if constexpr (MODE == 0) {
            hg[hi4] = Xl[lds];
        } else if constexpr (MODE == 1) {
            hg[hi4] = Xl[lds] + hg[hi4];
        } else {
            Xl[lds] = Xl[lds] + hg[hi4];   // combine into LDS for the FF
        }
    }

    if constexpr (MODE == 2) {
        __syncthreads();   // weights + combined h-tile visible

        // FF: out = relu(h@w0+b0)@w1 + b1, one position per thread, pure-FMA z-chunk form
        const int sw = t & 7;
        f4 h0[8], out[8];
        #pragma unroll
        for (int q = 0; q < 8; ++q) {
            h0[q]  = Xl[t * 8 + (q ^ sw)];
            out[q] = b1sh[q];
        }
        #pragma unroll 1
        for (int jc = 0; jc < 4; ++jc) {   // hidden chunk of 16 (4 f4)
            f4 z0 = b0sh[jc * 4 + 0], z1 = b0sh[jc * 4 + 1];
            f4 z2 = b0sh[jc * 4 + 2], z3 = b0sh[jc * 4 + 3];
            #pragma unroll
            for (int i = 0; i < 32; ++i) {
                float hi = h0[i >> 2][i & 3];
                z0 += su.ff.w0s[i * 16 + jc * 4 + 0] * hi;
                z1 += su.ff.w0s[i * 16 + jc * 4 + 1] * hi;
                z2 += su.ff.w0s[i * 16 + jc * 4 + 2] * hi;
                z3 += su.ff.w0s[i * 16 + jc * 4 + 3] * hi;
            }
            #pragma unroll
            for (int u = 0; u < 4; ++u) {
                f4 zu = (u == 0) ? z0 : (u == 1) ? z1 : (u == 2) ? z2 : z3;
                #pragma unroll
                for (int e = 0; e < 4; ++e) {
                    float zz = fmaxf(zu[e], 0.f);
                    int j = jc * 16 + u * 4 + e;
                    #pragma unroll
                    for (int q = 0; q < 8; ++q)
                        out[q] += su.ff.w1s[j * 8 + q] * zz;
                }
            }
        }
        #pragma unroll
        for (int q = 0; q < 8; ++q) Xl[t * 8 + (q ^ sw)] = out[q];   // exclusive slots
        __syncthreads();

        // final store, same it-sweep order
        #pragma unroll
        for (int it = 0; it < 8; ++it) {
            int n  = (t >> 3) + 32 * (it & 1);
            int s2 = it >> 1;
            int o4 = t & 7;
            f4 v = Xl[(s2 * 64 + n) * 8 + (o4 ^ (n & 7))];
            hg[((base + n * strideM + s2 * strideS) >> 2) + o4] = v;
        }
    }
}

extern "C" void kernel_launch(void* const* d_in, const int* in_sizes, int n_in,
                              void* d_out, int out_size, void* d_ws, size_t ws_size,
                              hipStream_t stream)
{
    const float* x   = (const float*)d_in[0];
    const float* fwx = (const float*)d_in[1];
    const float* fwy = (const float*)d_in[2];
    const float* fwz = (const float*)d_in[3];
    const float* w0  = (const float*)d_in[4];
    const float* b0  = (const float*)d_in[5];
    const float* w1  = (const float*)d_in[6];
    const float* b1  = (const float*)d_in[7];
    float* out = (float*)d_out;
    float* ws  = (float*)d_ws;

    if (ws_size < WS_FLOATS * sizeof(float)) return;

    init_kernel<<<(WS_FLOATS + 255) / 256, 256, 0, stream>>>(fwx, fwy, fwz, ws);
    // h accumulates in d_out (same shape/layout as output)
    axis_kernel<2, 0><<<GRID, 256, 0, stream>>>(x, out, ws, w0, w1, b0, b1);
    axis_kernel<1, 1><<<GRID, 256, 0, stream>>>(x, out, ws, w0, w1, b0, b1);
    axis_kernel<0, 2><<<GRID, 256, 0, stream>>>(x, out, ws, w0, w1, b0, b1);  // + fused FF
}

// Round 11
// 940.895 us; speedup vs baseline: 1.1732x; 1.1519x over previous
//
#include <hip/hip_runtime.h>
#include <math.h>

using f4 = __attribute__((ext_vector_type(4))) float;

// ws layout (floats)
#define OFF_D   0                    // 16*64 (unpadded)
#define OFF_WT  1024                 // 3 * 16384, rotated: [k][i][(o4+k)&7][ol]
#define WS_FLOATS (1024 + 3*16384)   // 50176
#define GRID 4096

__global__ __launch_bounds__(256) void init_kernel(
    const float* __restrict__ fw_x, const float* __restrict__ fw_y,
    const float* __restrict__ fw_z, float* __restrict__ ws)
{
    int gid = blockIdx.x * 256 + threadIdx.x;
    if (gid < 1024) {
        // D[k][n] = s_k * cos(pi * k * (2n+1) / 128), orthonormal DCT-II
        int k = gid >> 6, n = gid & 63;
        float s = (k == 0) ? 0.125f : sqrtf(2.0f / 64.0f);
        ws[OFF_D + gid] = s * cospif((float)((2 * n + 1) * k) / 128.0f);
    } else if (gid < WS_FLOATS) {
        int r = gid - 1024;
        int a = r / 16384;           // 0:z 1:y 2:x
        int q = r % 16384;
        int k = q >> 10, i = (q >> 5) & 31, o = q & 31;
        int o4 = o >> 2, ol = o & 3;
        int o4r = (o4 + k) & 7;      // rotate f4-slot by k: spreads phase-2 banks
        const float* fw = (a == 0) ? fw_z : (a == 1) ? fw_y : fw_x;  // fw[(i*32+o)*16+k]
        ws[OFF_WT + a * 16384 + k * 1024 + i * 32 + o4r * 4 + ol] = fw[(i * 32 + o) * 16 + k];
    }
}

// One block = 4 slabs (64 positions x 32 channels) along AXIS.
// h_slab = D^T @ mix_k( D_trunc @ X_slab ).
// MODE: 0 = write h, 1 = accumulate into h.  (FF is a separate kernel now —
// isolating the 6-7x HBM amplification that appeared only in the fused MODE=2.)
template<int AXIS, int MODE>
__global__ __launch_bounds__(256, 3) void axis_kernel(
    const float* __restrict__ x, float* __restrict__ h,
    const float* __restrict__ ws)
{
    __shared__ f4 Xl[2048];      // 32 KB: X tile during phases 1-2; h-tile afterwards
    __shared__ f4 Ul[512];       // 8 KB
    __shared__ f4 Vl[512];       // 8 KB
    __shared__ f4 Dl4[272];      // 4.25 KB: D padded, row stride 68 floats (17 f4)
    float* Dl = reinterpret_cast<float*>(Dl4);

    const int t = threadIdx.x;
    // XCD-aware bijective swizzle (GRID % 8 == 0)
    const int bid = (blockIdx.x & 7) * (GRID >> 3) + (blockIdx.x >> 3);
    const int b  = bid >> 10;
    const int c1 = (bid >> 4) & 63;
    const int c2 = bid & 15;

    const float* Dg = ws + OFF_D;
    const float* Wt = ws + OFF_WT + (AXIS == 2 ? 0 : AXIS == 1 ? 16384 : 2 * 16384);

    int base, strideM, strideS;
    if (AXIS == 2) { base = ((b * 64 + c1) * 64 + c2 * 4) * 2048; strideM = 32;     strideS = 2048; }
    if (AXIS == 1) { base = (b * 64 + c1) * 131072 + c2 * 128;    strideM = 2048;   strideS = 32; }
    if (AXIS == 0) { base = b * 8388608 + c1 * 2048 + c2 * 128;   strideM = 131072; strideS = 32; }

    // stage D with padded row stride (bank-spread for b32/b128 reads)
    #pragma unroll
    for (int q = 0; q < 4; ++q) {
        int idx = t + 256 * q;             // 0..1023
        int k = idx >> 6, n = idx & 63;
        Dl[k * 68 + n] = Dg[idx];
    }

    // stage X tile
    const f4* xg = reinterpret_cast<const f4*>(x);
    if (AXIS == 2) {
        int b4 = base >> 2;                // fully contiguous tile
        #pragma unroll
        for (int q = 0; q < 8; ++q) Xl[t + 256 * q] = xg[b4 + t + 256 * q];
    } else {
        #pragma unroll
        for (int q = 0; q < 8; ++q) {
            int j = t + 256 * q;
            int m = j >> 5, c = j & 31;    // per-m chunk: 128 contiguous floats [s][i]
            Xl[j] = xg[((base + m * strideM) >> 2) + c];
        }
    }
    __syncthreads();

    // Phase 1: U[s][k][i4] = sum_m D[k][m] * X[s][m][i4]; thread = (s,kp,i4), k = 2kp,2kp+1
    {
        const int i4 = t & 7, kp = (t >> 3) & 7, s = t >> 6;
        const int k0 = kp * 2;
        f4 a0 = {0.f, 0.f, 0.f, 0.f}, a1 = a0;
        #pragma unroll
        for (int mq = 0; mq < 16; ++mq) {
            f4 d0 = Dl4[k0 * 17 + mq];
            f4 d1 = Dl4[(k0 + 1) * 17 + mq];
            #pragma unroll
            for (int e = 0; e < 4; ++e) {
                int m = mq * 4 + e;
                f4 xv = Xl[AXIS == 2 ? (s * 512 + m * 8 + i4) : (m * 32 + s * 8 + i4)];
                a0 += xv * d0[e];
                a1 += xv * d1[e];
            }
        }
        Ul[s * 128 + k0 * 8 + i4] = a0;
        Ul[s * 128 + (k0 + 1) * 8 + i4] = a1;
    }
    __syncthreads();

    // Phase 2: V[s][k][o4] = sum_i U[s][k][i] * W[k][i][o4]; thread = (k,o4,sh)
    {
        const int k = t >> 4, o4 = (t >> 1) & 7, sh = t & 1;
        const int o4r = (o4 + k) & 7;      // matches init rotation
        const f4* Wt4 = reinterpret_cast<const f4*>(Wt);
        const float* Us = reinterpret_cast<const float*>(Ul);
        f4 v0 = {0.f, 0.f, 0.f, 0.f}, v1 = v0;
        #pragma unroll
        for (int ii = 0; ii < 32; ++ii) {
            int i = (ii + 4 * k) & 31;     // rotate loop start: spreads Us banks per k
            f4 w = Wt4[k * 256 + i * 8 + o4r];
            v0 += w * Us[(sh * 2) * 512 + k * 32 + i];
            v1 += w * Us[(sh * 2 + 1) * 512 + k * 32 + i];
        }
        Vl[(sh * 2) * 128 + k * 8 + o4] = v0;
        Vl[(sh * 2 + 1) * 128 + k * 8 + o4] = v1;
    }
    __syncthreads();

    // Phase 3 MAC (j-blocked, LDS-only output): acc[n] = sum_k D[k][n] * V[s][k][o4]
    {
        const int o4 = t & 7, nc = (t >> 3) & 7, s = t >> 6;
        f4 acc[8];
        #pragma unroll
        for (int j = 0; j < 8; ++j) acc[j] = f4{0.f, 0.f, 0.f, 0.f};
        #pragma unroll
        for (int k = 0; k < 16; ++k) {
            f4 v  = Vl[s * 128 + k * 8 + o4];
            f4 d0 = Dl4[k * 17 + nc * 2];
            f4 d1 = Dl4[k * 17 + nc * 2 + 1];
            acc[0] += v * d0[0]; acc[1] += v * d0[1];
            acc[2] += v * d0[2]; acc[3] += v * d0[3];
            acc[4] += v * d1[0]; acc[5] += v * d1[1];
            acc[6] += v * d1[2]; acc[7] += v * d1[3];
        }
        #pragma unroll
        for (int j = 0; j < 8; ++j) {
            int n = nc * 8 + j;
            Xl[(s * 64 + n) * 8 + (o4 ^ (n & 7))] = acc[j];
        }
    }
    __syncthreads();   // MAC done, h-tile staged in Xl

    // Global write / RMW in it-sweep order (measured clean for MODE 0/1)
    f4* hg = reinterpret_cast<f4*>(h);
    #pragma unroll
    for (int it = 0; it < 8; ++it) {
        int n  = (t >> 3) + 32 * (it & 1);
        int s2 = it >> 1;
        int o4 = t & 7;
        int lds = (s2 * 64 + n) * 8 + (o4 ^ (n & 7));
        int hi4 = ((base + n * strideM + s2 * strideS) >> 2) + o4;
        if constexpr (MODE == 0) hg[hi4] = Xl[lds];
        else                     hg[hi4] = Xl[lds] + hg[hi4];
    }
}

// Standalone FF: out = relu(h@w0+b0)@w1 + b1, in-place on d_out.
// Block owns 256 contiguous positions (32 KB tile: 256 pos x 128 B).
// Coalesced loads -> XOR-swizzled LDS -> 1 pos/thread.
__global__ __launch_bounds__(256, 3) void ff_kernel(
    float* __restrict__ h,
    const float* __restrict__ w0g, const float* __restrict__ w1g,
    const float* __restrict__ b0g, const float* __restrict__ b1g)
{
    __shared__ f4 Hl[2048];    // 32 KB: 256 positions x 8 f4, XOR-swizzled
    __shared__ f4 w0s[512];    // w0 natural [i][j4]  (i 0..31, j4 0..15)
    __shared__ f4 w1s[512];    // w1 natural [j][o4]  (j 0..63, o4 0..7)
    __shared__ f4 b0sh[16];
    __shared__ f4 b1sh[8];

    const int t = threadIdx.x;
    const int gbase = blockIdx.x * 2048;   // f4 index of block tile

    const f4* w0g4 = reinterpret_cast<const f4*>(w0g);
    const f4* w1g4 = reinterpret_cast<const f4*>(w1g);
    w0s[t] = w0g4[t];  w0s[t + 256] = w0g4[t + 256];
    w1s[t] = w1g4[t];  w1s[t + 256] = w1g4[t + 256];
    if (t < 16) b0sh[t] = reinterpret_cast<const f4*>(b0g)[t];
    else if (t < 24) b1sh[t - 16] = reinterpret_cast<const f4*>(b1g)[t - 16];

    // coalesced stage-in: global f4 g -> Hl[g ^ ((g>>3)&7)]
    f4* hg = reinterpret_cast<f4*>(h);
    #pragma unroll
    for (int q = 0; q < 8; ++q) {
        int j = t + 256 * q;
        Hl[j ^ ((j >> 3) & 7)] = hg[gbase + j];
    }
    __syncthreads();

    // per-thread FF on position t: gather h0[q] = Hl[t*8 + (q ^ (t&7))]
    const int sw = t & 7;
    f4 h0[8], out[8];
    #pragma unroll
    for (int q = 0; q < 8; ++q) {
        h0[q]  = Hl[t * 8 + (q ^ sw)];
        out[q] = b1sh[q];
    }
    #pragma unroll 1
    for (int jc = 0; jc < 4; ++jc) {       // hidden chunk of 16 (4 f4)
        f4 z0 = b0sh[jc * 4 + 0], z1 = b0sh[jc * 4 + 1];
        f4 z2 = b0sh[jc * 4 + 2], z3 = b0sh[jc * 4 + 3];
        #pragma unroll
        for (int i = 0; i < 32; ++i) {
            float hi = h0[i >> 2][i & 3];
            z0 += w0s[i * 16 + jc * 4 + 0] * hi;
            z1 += w0s[i * 16 + jc * 4 + 1] * hi;
            z2 += w0s[i * 16 + jc * 4 + 2] * hi;
            z3 += w0s[i * 16 + jc * 4 + 3] * hi;
        }
        #pragma unroll
        for (int u = 0; u < 4; ++u) {
            f4 zu = (u == 0) ? z0 : (u == 1) ? z1 : (u == 2) ? z2 : z3;
            #pragma unroll
            for (int e = 0; e < 4; ++e) {
                float zz = fmaxf(zu[e], 0.f);
                int j = jc * 16 + u * 4 + e;
                #pragma unroll
                for (int q = 0; q < 8; ++q)
                    out[q] += w1s[j * 8 + q] * zz;
            }
        }
    }
    #pragma unroll
    for (int q = 0; q < 8; ++q) Hl[t * 8 + (q ^ sw)] = out[q];   // exclusive slots
    __syncthreads();

    // coalesced stage-out (same mapping)
    #pragma unroll
    for (int q = 0; q < 8; ++q) {
        int j = t + 256 * q;
        hg[gbase + j] = Hl[j ^ ((j >> 3) & 7)];
    }
}

extern "C" void kernel_launch(void* const* d_in, const int* in_sizes, int n_in,
                              void* d_out, int out_size, void* d_ws, size_t ws_size,
                              hipStream_t stream)
{
    const float* x   = (const float*)d_in[0];
    const float* fwx = (const float*)d_in[1];
    const float* fwy = (const float*)d_in[2];
    const float* fwz = (const float*)d_in[3];
    const float* w0  = (const float*)d_in[4];
    const float* b0  = (const float*)d_in[5];
    const float* w1  = (const float*)d_in[6];
    const float* b1  = (const float*)d_in[7];
    float* out = (float*)d_out;
    float* ws  = (float*)d_ws;

    if (ws_size < WS_FLOATS * sizeof(float)) return;

    init_kernel<<<(WS_FLOATS + 255) / 256, 256, 0, stream>>>(fwx, fwy, fwz, ws);
    // h accumulates in d_out (same shape/layout as output)
    axis_kernel<2, 0><<<GRID, 256, 0, stream>>>(x, out, ws);
    axis_kernel<1, 1><<<GRID, 256, 0, stream>>>(x, out, ws);
    axis_kernel<0, 1><<<GRID, 256, 0, stream>>>(x, out, ws);
    ff_kernel<<<GRID, 256, 0, stream>>>(out, w0, w1, b0, b1);
}